// Round 7
// baseline (76.193 us; speedup 1.0000x reference)
//
#include <hip/hip_runtime.h>

// out[b, t, c] = data[(index[b] + t) % cycle_len][c]
// B=2048, L=720, C=64 (fp32). 377 MB pure write stream.
//
// R7 = R4 (global grid-stride store order, plain stores — the proven best:
// 67.1us / 5.63 TB/s) with ONE change: grid 1024 -> 2048 blocks (8/CU,
// 32 waves/CU). Mechanism: our store issue is gated behind two dependent
// L1-hit loads per iteration; doubling resident waves doubles the
// outstanding-store pool feeding the HBM controllers. Read-path variants
// (LDS/registers/NT) all proved neutral or negative in R2/R3/R5/R6.

using f4 = __attribute__((ext_vector_type(4))) float;

constexpr int CCH   = 64;         // channels
constexpr int C4    = CCH / 4;    // float4 per row = 16
constexpr int BLOCK = 256;
constexpr unsigned GRIDB = 2048;  // 8 blocks/CU, 8 MB moving window

// Fast path: all divisors compile-time.
template <unsigned ROWF4, unsigned CYC, unsigned ITERS>
__global__ __launch_bounds__(BLOCK) void rc_stride(
    const int* __restrict__ index,
    const f4*  __restrict__ data4,   // [CYC][C4]
    f4*        __restrict__ out4)    // flat [B*L*C4]
{
    const unsigned G = GRIDB * BLOCK;            // 524288 threads
    unsigned p = blockIdx.x * BLOCK + threadIdx.x;
    #pragma unroll 4
    for (unsigned i = 0; i < ITERS; ++i, p += G) {
        unsigned b   = p / ROWF4;                // magic mul
        unsigned q   = p - b * ROWF4;
        unsigned t   = q >> 4;
        unsigned c4  = q & (C4 - 1);
        unsigned row = ((unsigned)index[b] + t) % CYC;   // magic mul
        out4[p] = data4[row * C4 + c4];          // L1/L2-hit (43 KB table)
    }
}

// Generic fallback (R1-style, correct for any shape).
__global__ __launch_bounds__(BLOCK) void rc_generic(
    const int* __restrict__ index,
    const f4*  __restrict__ data4,
    f4*        __restrict__ out4,
    int L, int cycle_len)
{
    const int tid = threadIdx.x;
    const int b   = blockIdx.x;
    const int idx = index[b];
    f4* outb = out4 + (size_t)b * (size_t)L * C4;
    const int n  = L * C4;
    const int t0 = tid >> 4;
    const int c4 = tid & (C4 - 1);
    int row = (idx + t0) % cycle_len;
    const int rstep = (BLOCK / C4) % cycle_len;
    for (int p = tid; p < n; p += BLOCK) {
        outb[p] = data4[row * C4 + c4];
        row += rstep;
        if (row >= cycle_len) row -= cycle_len;
    }
}

extern "C" void kernel_launch(void* const* d_in, const int* in_sizes, int n_in,
                              void* d_out, int out_size, void* d_ws, size_t ws_size,
                              hipStream_t stream) {
    // setup_inputs order: index [B] int32, length scalar (derived), data fp32.
    const int*   index = (const int*)d_in[0];
    const float* data  = (const float*)d_in[2];

    const int B         = in_sizes[0];
    const int cycle_len = in_sizes[2] / CCH;      // 168
    const int L         = out_size / (B * CCH);   // 720

    if (B == 2048 && L == 720 && cycle_len == 168) {
        // total f4 = 2048*720*16 = 23,592,960 = (2048*256) * 45 exactly
        rc_stride<720 * C4, 168, 45><<<GRIDB, BLOCK, 0, stream>>>(
            index, (const f4*)data, (f4*)d_out);
    } else {
        rc_generic<<<B, BLOCK, 0, stream>>>(
            index, (const f4*)data, (f4*)d_out, L, cycle_len);
    }
}

// Round 8
// 69.780 us; speedup vs baseline: 1.0919x; 1.0919x over previous
//
#include <hip/hip_runtime.h>

// out[b, t, c] = data[(index[b] + t) % cycle_len][c]
// B=2048, L=720, C=64 (fp32). 377 MB pure write stream.
//
// R8 = R4 (global grid-stride order, plain stores, best: 67.1us) with ONE
// change: grid 1024 -> 512 blocks (2/CU, 8 waves/CU, 2 MB instantaneous
// write window). Evidence: 2048 blocks (8 MB window) = 76us, 1024 (4 MB)
// = 67us -> fewer interleaved wave streams / tighter window = better DRAM
// page locality at the memory controllers. fillBufferAligned sustains
// 7.0 TB/s at ~11% occupancy (~4 waves/CU). Issue-rate check: at 7 TB/s a
// CU needs one wave-store per ~90cy; 8 waves/CU x 4-deep unroll issues far
// faster than that even with L2-hit read latency.

using f4 = __attribute__((ext_vector_type(4))) float;

constexpr int CCH   = 64;         // channels
constexpr int C4    = CCH / 4;    // float4 per row = 16
constexpr int BLOCK = 256;
constexpr unsigned GRIDB = 512;   // 2 blocks/CU, 2 MB moving window

// Fast path: all divisors compile-time.
template <unsigned ROWF4, unsigned CYC, unsigned ITERS>
__global__ __launch_bounds__(BLOCK) void rc_stride(
    const int* __restrict__ index,
    const f4*  __restrict__ data4,   // [CYC][C4]
    f4*        __restrict__ out4)    // flat [B*L*C4]
{
    const unsigned G = GRIDB * BLOCK;            // 131072 threads
    unsigned p = blockIdx.x * BLOCK + threadIdx.x;
    #pragma unroll 4
    for (unsigned i = 0; i < ITERS; ++i, p += G) {
        unsigned b   = p / ROWF4;                // magic mul
        unsigned q   = p - b * ROWF4;
        unsigned t   = q >> 4;
        unsigned c4  = q & (C4 - 1);
        unsigned row = ((unsigned)index[b] + t) % CYC;   // magic mul
        out4[p] = data4[row * C4 + c4];          // L1/L2-hit (43 KB table)
    }
}

// Generic fallback (R1-style, correct for any shape).
__global__ __launch_bounds__(BLOCK) void rc_generic(
    const int* __restrict__ index,
    const f4*  __restrict__ data4,
    f4*        __restrict__ out4,
    int L, int cycle_len)
{
    const int tid = threadIdx.x;
    const int b   = blockIdx.x;
    const int idx = index[b];
    f4* outb = out4 + (size_t)b * (size_t)L * C4;
    const int n  = L * C4;
    const int t0 = tid >> 4;
    const int c4 = tid & (C4 - 1);
    int row = (idx + t0) % cycle_len;
    const int rstep = (BLOCK / C4) % cycle_len;
    for (int p = tid; p < n; p += BLOCK) {
        outb[p] = data4[row * C4 + c4];
        row += rstep;
        if (row >= cycle_len) row -= cycle_len;
    }
}

extern "C" void kernel_launch(void* const* d_in, const int* in_sizes, int n_in,
                              void* d_out, int out_size, void* d_ws, size_t ws_size,
                              hipStream_t stream) {
    // setup_inputs order: index [B] int32, length scalar (derived), data fp32.
    const int*   index = (const int*)d_in[0];
    const float* data  = (const float*)d_in[2];

    const int B         = in_sizes[0];
    const int cycle_len = in_sizes[2] / CCH;      // 168
    const int L         = out_size / (B * CCH);   // 720

    if (B == 2048 && L == 720 && cycle_len == 168) {
        // total f4 = 2048*720*16 = 23,592,960 = (512*256) * 180 exactly
        rc_stride<720 * C4, 168, 180><<<GRIDB, BLOCK, 0, stream>>>(
            index, (const f4*)data, (f4*)d_out);
    } else {
        rc_generic<<<B, BLOCK, 0, stream>>>(
            index, (const f4*)data, (f4*)d_out, L, cycle_len);
    }
}

// Round 9
// 67.474 us; speedup vs baseline: 1.1292x; 1.0342x over previous
//
#include <hip/hip_runtime.h>

// out[b, t, c] = data[(index[b] + t) % cycle_len][c]
// B=2048, L=720, C=64 (fp32). 377 MB pure write stream.
//
// R8 = R4 (global grid-stride order, plain stores, best: 67.1us) with ONE
// change: grid 1024 -> 512 blocks (2/CU, 8 waves/CU, 2 MB instantaneous
// write window). Evidence: 2048 blocks (8 MB window) = 76us, 1024 (4 MB)
// = 67us -> fewer interleaved wave streams / tighter window = better DRAM
// page locality at the memory controllers. fillBufferAligned sustains
// 7.0 TB/s at ~11% occupancy (~4 waves/CU). Issue-rate check: at 7 TB/s a
// CU needs one wave-store per ~90cy; 8 waves/CU x 4-deep unroll issues far
// faster than that even with L2-hit read latency.

using f4 = __attribute__((ext_vector_type(4))) float;

constexpr int CCH   = 64;         // channels
constexpr int C4    = CCH / 4;    // float4 per row = 16
constexpr int BLOCK = 256;
constexpr unsigned GRIDB = 512;   // 2 blocks/CU, 2 MB moving window

// Fast path: all divisors compile-time.
template <unsigned ROWF4, unsigned CYC, unsigned ITERS>
__global__ __launch_bounds__(BLOCK) void rc_stride(
    const int* __restrict__ index,
    const f4*  __restrict__ data4,   // [CYC][C4]
    f4*        __restrict__ out4)    // flat [B*L*C4]
{
    const unsigned G = GRIDB * BLOCK;            // 131072 threads
    unsigned p = blockIdx.x * BLOCK + threadIdx.x;
    #pragma unroll 4
    for (unsigned i = 0; i < ITERS; ++i, p += G) {
        unsigned b   = p / ROWF4;                // magic mul
        unsigned q   = p - b * ROWF4;
        unsigned t   = q >> 4;
        unsigned c4  = q & (C4 - 1);
        unsigned row = ((unsigned)index[b] + t) % CYC;   // magic mul
        out4[p] = data4[row * C4 + c4];          // L1/L2-hit (43 KB table)
    }
}

// Generic fallback (R1-style, correct for any shape).
__global__ __launch_bounds__(BLOCK) void rc_generic(
    const int* __restrict__ index,
    const f4*  __restrict__ data4,
    f4*        __restrict__ out4,
    int L, int cycle_len)
{
    const int tid = threadIdx.x;
    const int b   = blockIdx.x;
    const int idx = index[b];
    f4* outb = out4 + (size_t)b * (size_t)L * C4;
    const int n  = L * C4;
    const int t0 = tid >> 4;
    const int c4 = tid & (C4 - 1);
    int row = (idx + t0) % cycle_len;
    const int rstep = (BLOCK / C4) % cycle_len;
    for (int p = tid; p < n; p += BLOCK) {
        outb[p] = data4[row * C4 + c4];
        row += rstep;
        if (row >= cycle_len) row -= cycle_len;
    }
}

extern "C" void kernel_launch(void* const* d_in, const int* in_sizes, int n_in,
                              void* d_out, int out_size, void* d_ws, size_t ws_size,
                              hipStream_t stream) {
    // setup_inputs order: index [B] int32, length scalar (derived), data fp32.
    const int*   index = (const int*)d_in[0];
    const float* data  = (const float*)d_in[2];

    const int B         = in_sizes[0];
    const int cycle_len = in_sizes[2] / CCH;      // 168
    const int L         = out_size / (B * CCH);   // 720

    if (B == 2048 && L == 720 && cycle_len == 168) {
        // total f4 = 2048*720*16 = 23,592,960 = (512*256) * 180 exactly
        rc_stride<720 * C4, 168, 180><<<GRIDB, BLOCK, 0, stream>>>(
            index, (const f4*)data, (f4*)d_out);
    } else {
        rc_generic<<<B, BLOCK, 0, stream>>>(
            index, (const f4*)data, (f4*)d_out, L, cycle_len);
    }
}